// Round 1
// baseline (37997.455 us; speedup 1.0000x reference)
//
#include <hip/hip_runtime.h>

// MultiRegionRNN: T=512, B=128, D_IN=64, N=512, D_OUT=2, ALPHA=0.1
// Persistent cooperative kernel: 511 sequential steps with custom grid barrier.
// Layouts (built in phase 0):
//   g_Wcat[R][k][n] : k-major concat [rec(512) | inter(512) | (A only) input(64)]
//   g_XT[t][d][b]   : X transposed so lane<->b reads are coalesced
//   g_r[buf][R][n][b] : rates transposed (n-major), ping-pong buffers
// Per step: WG = (region R, 16 cols, 64 b). Waves split K. W via wave-uniform
// s_load (SGPR operand FMA), r via per-lane coalesced b32 loads. x-state in regs.

#define NWG   192
#define NTHR  256
#define NREG  3
#define NN    512
#define BB    128
#define TT    512
#define DIN   64
#define KA    1088
#define KBC   1024

__device__ float g_Wcat[3][1088][512];   // 6.7 MB
__device__ float g_XT[512][64][128];     // 16.8 MB (row t=0 unused)
__device__ float g_r[2][3][512][128];    // 1.5 MB ping-pong rates

__device__ __forceinline__ float fast_tanh(float x) {
    // tanh(x) = 1 - 2/(e^{2x}+1); monotone, saturates to +-1, no NaN.
    float e = __expf(2.0f * x);
    return 1.0f - 2.0f / (e + 1.0f);
}

__device__ __forceinline__ void grid_barrier(unsigned* cnt, unsigned target) {
    __syncthreads();  // drains vmcnt for all waves of this WG (stores acked to L2)
    if (threadIdx.x == 0) {
        // agent-release RMW: writes back this XCD's L2 before bumping counter
        __hip_atomic_fetch_add(cnt, 1u, __ATOMIC_RELEASE, __HIP_MEMORY_SCOPE_AGENT);
        // relaxed spin (no per-poll cache invalidate), acquire fence once on exit
        while ((int)(__hip_atomic_load(cnt, __ATOMIC_RELAXED, __HIP_MEMORY_SCOPE_AGENT) - target) < 0) {
            __builtin_amdgcn_s_sleep(1);
        }
        __builtin_amdgcn_fence(__ATOMIC_ACQUIRE, "agent");
    }
    __syncthreads();
}

__device__ __forceinline__ void seg_accum(const float* __restrict__ rbase,
                                          const float* __restrict__ wbase,
                                          int nk, int b, float acc[16]) {
    #pragma unroll 8
    for (int kk = 0; kk < nk; ++kk) {
        float rv = rbase[kk * 128 + b];                       // per-lane, coalesced
        const float4* wr4 = (const float4*)(wbase + kk * 512); // wave-uniform -> s_load
        float4 w0 = wr4[0], w1 = wr4[1], w2 = wr4[2], w3 = wr4[3];
        acc[0]  = fmaf(w0.x, rv, acc[0]);  acc[1]  = fmaf(w0.y, rv, acc[1]);
        acc[2]  = fmaf(w0.z, rv, acc[2]);  acc[3]  = fmaf(w0.w, rv, acc[3]);
        acc[4]  = fmaf(w1.x, rv, acc[4]);  acc[5]  = fmaf(w1.y, rv, acc[5]);
        acc[6]  = fmaf(w1.z, rv, acc[6]);  acc[7]  = fmaf(w1.w, rv, acc[7]);
        acc[8]  = fmaf(w2.x, rv, acc[8]);  acc[9]  = fmaf(w2.y, rv, acc[9]);
        acc[10] = fmaf(w2.z, rv, acc[10]); acc[11] = fmaf(w2.w, rv, acc[11]);
        acc[12] = fmaf(w3.x, rv, acc[12]); acc[13] = fmaf(w3.y, rv, acc[13]);
        acc[14] = fmaf(w3.z, rv, acc[14]); acc[15] = fmaf(w3.w, rv, acc[15]);
    }
}

extern "C" __global__ void __launch_bounds__(NTHR)
rnn_kernel(const float* __restrict__ X,
           const float* __restrict__ Wra, const float* __restrict__ Wrb,
           const float* __restrict__ Wrc, const float* __restrict__ Wab,
           const float* __restrict__ Wbc, const float* __restrict__ Wca,
           const float* __restrict__ Wina, const float* __restrict__ Woutc,
           float* __restrict__ out, unsigned* __restrict__ bar) {
    const int tid = threadIdx.x;
    const int wg  = blockIdx.x;
    const int gthreads = NWG * NTHR;
    const int gid = wg * NTHR + tid;

    // ---------------- phase 0: layout building (fully parallel) ----------------
    // Wcat[R][k][n]: k<512 rec; 512..1023 inter (A<-W_CA, B<-W_AB, C<-W_BC); A: 1024..1087 W_in
    for (int i = gid; i < 3 * 1088 * 512; i += gthreads) {
        int R   = i / (1088 * 512);
        int rem = i - R * (1088 * 512);
        int k = rem >> 9;
        int n = rem & 511;
        float v = 0.0f;
        if (R == 0) {
            if (k < 512)       v = Wra[n * 512 + k];
            else if (k < 1024) v = Wca[n * 512 + (k - 512)];
            else               v = Wina[n * 64 + (k - 1024)];
        } else if (R == 1) {
            if (k < 512)       v = Wrb[n * 512 + k];
            else if (k < 1024) v = Wab[n * 512 + (k - 512)];
        } else {
            if (k < 512)       v = Wrc[n * 512 + k];
            else if (k < 1024) v = Wbc[n * 512 + (k - 512)];
        }
        g_Wcat[R][k][n] = v;
    }
    // XT[t][d][b] = X[t][b][d], t = 1..511
    for (int i = gid; i < 511 * 64 * 128; i += gthreads) {
        int t   = i / (64 * 128) + 1;
        int rem = i & (64 * 128 - 1);
        int d = rem >> 7;
        int b = rem & 127;
        g_XT[t][d][b] = X[(t * 128 + b) * 64 + d];
    }
    // zero r(t=0) buffer and output (output needed: we accumulate via atomics)
    {
        float* r0 = &g_r[0][0][0][0];
        for (int i = gid; i < 3 * 512 * 128; i += gthreads) r0[i] = 0.0f;
        for (int i = gid; i < 511 * 128 * 2; i += gthreads) out[i] = 0.0f;
    }

    // ---------------- decomposition ----------------
    const int R    = wg >> 6;          // 0..2 (64 WGs per region)
    const int cg   = (wg >> 1) & 31;   // col group (16 cols each)
    const int bh   = wg & 1;           // batch half
    const int n0   = cg * 16;
    const int b0   = bh * 64;
    const int w    = __builtin_amdgcn_readfirstlane(tid >> 6); // wave id 0..3
    const int lane = tid & 63;
    const int b    = b0 + lane;
    const int src2 = (R + 2) % 3;      // inter source: A<-C, B<-A, C<-B
    const int c_own = tid >> 4;        // 0..15: owned column for reduce/update
    const int bs    = (tid & 15) << 2; // owned batch quad
    float4 xq = make_float4(0.f, 0.f, 0.f, 0.f);  // persistent state in regs

    __shared__ float part[4][16][64];     // K-split partials (16 KB)
    __shared__ float part2[16][64][2];    // readout partials (8 KB)

    grid_barrier(bar, (unsigned)NWG);     // epoch 0: phase 0 published

    for (int t = 1; t < 512; ++t) {
        const int prev = (t + 1) & 1;
        const int cur  = t & 1;
        float acc[16];
        #pragma unroll
        for (int c = 0; c < 16; ++c) acc[c] = 0.0f;

        // seg1: own-region recurrent, k rows [w*128, w*128+128)
        seg_accum(&g_r[prev][R][w * 128][0], &g_Wcat[R][w * 128][n0], 128, b, acc);
        // seg2: inter-region, k rows [512+w*128, ...)
        seg_accum(&g_r[prev][src2][w * 128][0], &g_Wcat[R][512 + w * 128][n0], 128, b, acc);
        // seg3 (region A only): input projection rows
        if (R == 0) {
            seg_accum(&g_XT[t][w * 16][0], &g_Wcat[0][1024 + w * 16][n0], 16, b, acc);
        }

        // ---- cross-wave K reduction ----
        #pragma unroll
        for (int c = 0; c < 16; ++c) part[w][c][lane] = acc[c];
        __syncthreads();

        float4 s0 = *(const float4*)&part[0][c_own][bs];
        float4 s1 = *(const float4*)&part[1][c_own][bs];
        float4 s2 = *(const float4*)&part[2][c_own][bs];
        float4 s3 = *(const float4*)&part[3][c_own][bs];
        float4 sum;
        sum.x = (s0.x + s1.x) + (s2.x + s3.x);
        sum.y = (s0.y + s1.y) + (s2.y + s3.y);
        sum.z = (s0.z + s1.z) + (s2.z + s3.z);
        sum.w = (s0.w + s1.w) + (s2.w + s3.w);

        // leaky state update + tanh (x kept in registers across all steps)
        xq.x = 0.9f * xq.x + 0.1f * sum.x;
        xq.y = 0.9f * xq.y + 0.1f * sum.y;
        xq.z = 0.9f * xq.z + 0.1f * sum.z;
        xq.w = 0.9f * xq.w + 0.1f * sum.w;
        float4 r4;
        r4.x = fast_tanh(xq.x); r4.y = fast_tanh(xq.y);
        r4.z = fast_tanh(xq.z); r4.w = fast_tanh(xq.w);
        *(float4*)&g_r[cur][R][n0 + c_own][b0 + bs] = r4;

        // ---- fused readout (region C WGs): out[t-1][b][d] += rC . Wout[d] ----
        if (R == 2) {
            float w0 = Woutc[0 * 512 + n0 + c_own];
            float w1 = Woutc[1 * 512 + n0 + c_own];
            part2[c_own][bs + 0][0] = r4.x * w0; part2[c_own][bs + 0][1] = r4.x * w1;
            part2[c_own][bs + 1][0] = r4.y * w0; part2[c_own][bs + 1][1] = r4.y * w1;
            part2[c_own][bs + 2][0] = r4.z * w0; part2[c_own][bs + 2][1] = r4.z * w1;
            part2[c_own][bs + 3][0] = r4.w * w0; part2[c_own][bs + 3][1] = r4.w * w1;
            __syncthreads();
            if (tid < 128) {
                int bb = tid >> 1, d = tid & 1;
                float s = 0.0f;
                #pragma unroll
                for (int c = 0; c < 16; ++c) s += part2[c][bb][d];
                atomicAdd(&out[(t - 1) * 256 + (b0 + bb) * 2 + d], s);
            }
        }

        if (t < 511) grid_barrier(bar, (unsigned)(NWG * (t + 1)));
    }
}

extern "C" void kernel_launch(void* const* d_in, const int* in_sizes, int n_in,
                              void* d_out, int out_size, void* d_ws, size_t ws_size,
                              hipStream_t stream) {
    const float* X    = (const float*)d_in[0];
    const float* Wra  = (const float*)d_in[1];
    const float* Wrb  = (const float*)d_in[2];
    const float* Wrc  = (const float*)d_in[3];
    const float* Wab  = (const float*)d_in[4];
    const float* Wbc  = (const float*)d_in[5];
    const float* Wca  = (const float*)d_in[6];
    const float* Wina = (const float*)d_in[7];
    const float* Wout = (const float*)d_in[8];
    float* out = (float*)d_out;
    unsigned* bar = (unsigned*)d_ws;

    hipMemsetAsync(bar, 0, sizeof(unsigned), stream);  // deterministic barrier base

    void* args[] = { (void*)&X, (void*)&Wra, (void*)&Wrb, (void*)&Wrc,
                     (void*)&Wab, (void*)&Wbc, (void*)&Wca, (void*)&Wina,
                     (void*)&Wout, (void*)&out, (void*)&bar };
    hipLaunchCooperativeKernel((const void*)rnn_kernel, dim3(NWG), dim3(NTHR),
                               args, 0, stream);
}